// Round 2
// baseline (53.888 us; speedup 1.0000x reference)
//
#include <hip/hip_runtime.h>
#include <hip/hip_bf16.h>

// Problem constants (DeepseekV4HashRouter): B=4,S=4096,D=2048,E=256,K=8,V=128000
#define DIM   2048
#define NEXP  256
#define TOPK  8
#define RSCALE 2.5f

__device__ __forceinline__ ushort f2bf(float f) {
    unsigned int u = __float_as_uint(f);
    unsigned int r = (u + 0x7FFFu + ((u >> 16) & 1u)) >> 16;  // RNE
    return (ushort)r;
}
__device__ __forceinline__ float bf2f(ushort s) {
    return __uint_as_float(((unsigned int)s) << 16);
}

__global__ __launch_bounds__(256) void convert_weight_kernel(
    const float* __restrict__ w, ushort* __restrict__ wb, int n4) {
    int i = blockIdx.x * blockDim.x + threadIdx.x;
    if (i < n4) {
        float4 f = reinterpret_cast<const float4*>(w)[i];
        ushort4 u;
        u.x = f2bf(f.x); u.y = f2bf(f.y); u.z = f2bf(f.z); u.w = f2bf(f.w);
        reinterpret_cast<ushort4*>(wb)[i] = u;
    }
}

// One block (256 threads) per token.
template <bool BF16W>
__global__ __launch_bounds__(256) void router_kernel(
    const float* __restrict__ hidden,       // [N, D]
    const int* __restrict__ token_ids,      // [N]  (harness passes int32)
    const void* __restrict__ weight,        // [E, D] (float or bf16-as-ushort)
    const int* __restrict__ tid2eid,        // [V, K]
    float* __restrict__ out,                // probs [N,E] then map [N,E]
    int N) {
    const int n = blockIdx.x;
    const int t = threadIdx.x;

    __shared__ int   s_idx[TOPK];
    __shared__ float s_red[4][TOPK];
    __shared__ float s_sc[TOPK];

    if (t < TOPK) {
        int tid = token_ids[n];
        s_idx[t] = tid2eid[(size_t)tid * TOPK + t];
    }
    __syncthreads();

    // Each thread owns 8 hidden elements: [t*4, t*4+4) and [1024+t*4, ...)
    const float* hrow = hidden + (size_t)n * DIM;
    const float4 h0 = reinterpret_cast<const float4*>(hrow)[t];
    const float4 h1 = reinterpret_cast<const float4*>(hrow + 1024)[t];

    float acc[TOPK];
#pragma unroll
    for (int k = 0; k < TOPK; ++k) {
        const int e = s_idx[k];
        float4 w0, w1;
        if (BF16W) {
            const ushort* wrow = reinterpret_cast<const ushort*>(weight) + (size_t)e * DIM;
            ushort4 a = reinterpret_cast<const ushort4*>(wrow)[t];
            ushort4 b = reinterpret_cast<const ushort4*>(wrow + 1024)[t];
            w0 = make_float4(bf2f(a.x), bf2f(a.y), bf2f(a.z), bf2f(a.w));
            w1 = make_float4(bf2f(b.x), bf2f(b.y), bf2f(b.z), bf2f(b.w));
        } else {
            const float* wrow = reinterpret_cast<const float*>(weight) + (size_t)e * DIM;
            w0 = reinterpret_cast<const float4*>(wrow)[t];
            w1 = reinterpret_cast<const float4*>(wrow + 1024)[t];
        }
        acc[k] = h0.x * w0.x + h0.y * w0.y + h0.z * w0.z + h0.w * w0.w
               + h1.x * w1.x + h1.y * w1.y + h1.z * w1.z + h1.w * w1.w;
    }

    // Wave (64-lane) reduce, then cross-wave via LDS.
#pragma unroll
    for (int k = 0; k < TOPK; ++k) {
#pragma unroll
        for (int off = 32; off > 0; off >>= 1)
            acc[k] += __shfl_down(acc[k], off, 64);
    }
    const int wave = t >> 6;
    const int lane = t & 63;
    if (lane == 0) {
#pragma unroll
        for (int k = 0; k < TOPK; ++k) s_red[wave][k] = acc[k];
    }
    __syncthreads();

    if (t < TOPK) {
        float logit = s_red[0][t] + s_red[1][t] + s_red[2][t] + s_red[3][t];
        // numerically stable softplus: max(x,0) + log1p(exp(-|x|))
        float sp = fmaxf(logit, 0.0f) + log1pf(expf(-fabsf(logit)));
        s_sc[t] = sqrtf(sp);
    }
    __syncthreads();

    float denom = 0.0f;
#pragma unroll
    for (int k = 0; k < TOPK; ++k) denom += s_sc[k];
    denom = fmaxf(denom, 1e-12f);
    const float inv = RSCALE / denom;

    // Dense write: expert id == thread id (E == 256 == blockDim).
    float p = 0.0f, m = 0.0f;
#pragma unroll
    for (int k = 0; k < TOPK; ++k) {
        if (s_idx[k] == t) { p = s_sc[k] * inv; m = 1.0f; }
    }
    const size_t off = (size_t)n * NEXP + t;
    out[off] = p;
    out[(size_t)N * NEXP + off] = m;
}

extern "C" void kernel_launch(void* const* d_in, const int* in_sizes, int n_in,
                              void* d_out, int out_size, void* d_ws, size_t ws_size,
                              hipStream_t stream) {
    const float* hidden    = (const float*)d_in[0];
    const int*   token_ids = (const int*)d_in[1];   // int64 in ref -> int32 here
    const float* weight    = (const float*)d_in[2];
    const int*   tid2eid   = (const int*)d_in[3];
    float* out = (float*)d_out;
    const int N = in_sizes[1];  // B*S tokens

    const size_t need = (size_t)NEXP * DIM * sizeof(ushort);  // 1 MiB
    if (ws_size >= need) {
        ushort* wb = (ushort*)d_ws;
        const int n4 = NEXP * DIM / 4;
        convert_weight_kernel<<<(n4 + 255) / 256, 256, 0, stream>>>(weight, wb, n4);
        router_kernel<true><<<N, 256, 0, stream>>>(hidden, token_ids, wb, tid2eid, out, N);
    } else {
        router_kernel<false><<<N, 256, 0, stream>>>(hidden, token_ids, weight, tid2eid, out, N);
    }
}

// Round 3
// 52.147 us; speedup vs baseline: 1.0334x; 1.0334x over previous
//
#include <hip/hip_runtime.h>
#include <hip/hip_bf16.h>

// DeepseekV4HashRouter: B=4,S=4096,D=2048,E=256,K=8,V=128000
#define DIM    2048
#define NEXP   256
#define TOPK   8
#define RSCALE 2.5f
#define WPT    4  // waves (tokens) per 256-thread block

__device__ __forceinline__ ushort f2bf(float f) {
    unsigned int u = __float_as_uint(f);
    unsigned int r = (u + 0x7FFFu + ((u >> 16) & 1u)) >> 16;  // RNE
    return (ushort)r;
}
__device__ __forceinline__ float bflo(unsigned int u) {
    return __uint_as_float(u << 16);
}
__device__ __forceinline__ float bfhi(unsigned int u) {
    return __uint_as_float(u & 0xFFFF0000u);
}

__global__ __launch_bounds__(256) void convert_weight_kernel(
    const float* __restrict__ w, ushort* __restrict__ wb, int n4) {
    int i = blockIdx.x * blockDim.x + threadIdx.x;
    if (i < n4) {
        float4 f = reinterpret_cast<const float4*>(w)[i];
        ushort4 u;
        u.x = f2bf(f.x); u.y = f2bf(f.y); u.z = f2bf(f.z); u.w = f2bf(f.w);
        reinterpret_cast<ushort4*>(wb)[i] = u;
    }
}

// One 64-lane wave per token. Lane l owns hidden elems {j*512 + l*8 .. +7}.
template <bool BF16W>
__global__ __launch_bounds__(256) void router_wave_kernel(
    const float* __restrict__ hidden,   // [N, D] fp32
    const int* __restrict__ token_ids,  // [N] int32
    const void* __restrict__ weight,    // [E, D] bf16(ushort) or fp32
    const int* __restrict__ tid2eid,    // [V, K] int32
    float* __restrict__ out,            // probs [N,E] then map [N,E]
    int N) {
    const int wave = threadIdx.x >> 6;
    const int lane = threadIdx.x & 63;
    const int n = blockIdx.x * WPT + wave;
    if (n >= N) return;

    // Expert ids: same-address broadcast loads across the wave.
    const int tid = token_ids[n];
    const int4* erow = reinterpret_cast<const int4*>(tid2eid + (size_t)tid * TOPK);
    const int4 i0 = erow[0];
    const int4 i1 = erow[1];
    const int eidx[TOPK] = {i0.x, i0.y, i0.z, i0.w, i1.x, i1.y, i1.z, i1.w};

    // Preload this lane's 32 hidden elements (8 x float4).
    const float4* h4 = reinterpret_cast<const float4*>(hidden + (size_t)n * DIM);
    float4 h[8];
#pragma unroll
    for (int j = 0; j < 4; ++j) {
        h[2 * j]     = h4[j * 128 + lane * 2];
        h[2 * j + 1] = h4[j * 128 + lane * 2 + 1];
    }

    float acc[TOPK];
#pragma unroll
    for (int k = 0; k < TOPK; ++k) {
        const int e = eidx[k];
        float s = 0.0f;
        if (BF16W) {
            const uint4* wrow = reinterpret_cast<const uint4*>(weight) + (size_t)e * (DIM / 8);
#pragma unroll
            for (int j = 0; j < 4; ++j) {
                const uint4 w = wrow[j * 64 + lane];  // 8 bf16, coalesced 1KB/wave
                const float4 a = h[2 * j];
                const float4 b = h[2 * j + 1];
                s += a.x * bflo(w.x) + a.y * bfhi(w.x)
                   + a.z * bflo(w.y) + a.w * bfhi(w.y)
                   + b.x * bflo(w.z) + b.y * bfhi(w.z)
                   + b.z * bflo(w.w) + b.w * bfhi(w.w);
            }
        } else {
            const float4* wrow = reinterpret_cast<const float4*>(weight) + (size_t)e * (DIM / 4);
#pragma unroll
            for (int j = 0; j < 4; ++j) {
                const float4 wa = wrow[j * 128 + lane * 2];
                const float4 wb = wrow[j * 128 + lane * 2 + 1];
                const float4 a = h[2 * j];
                const float4 b = h[2 * j + 1];
                s += a.x * wa.x + a.y * wa.y + a.z * wa.z + a.w * wa.w
                   + b.x * wb.x + b.y * wb.y + b.z * wb.z + b.w * wb.w;
            }
        }
        acc[k] = s;
    }

    // Butterfly reduce: every lane ends with the full dot for all 8 experts.
#pragma unroll
    for (int k = 0; k < TOPK; ++k) {
        float v = acc[k];
#pragma unroll
        for (int m = 1; m < 64; m <<= 1) v += __shfl_xor(v, m, 64);
        acc[k] = v;
    }

    // Lanes 0..7 compute sqrt(softplus(logit)) for expert slot = lane.
    float s_own = 0.0f;
    if (lane < TOPK) {
        const float logit = acc[lane];
        const float sp = fmaxf(logit, 0.0f) + log1pf(expf(-fabsf(logit)));
        s_own = sqrtf(sp);
    }
    float sc[TOPK];
    float denom = 0.0f;
#pragma unroll
    for (int k = 0; k < TOPK; ++k) {
        sc[k] = __shfl(s_own, k, 64);
        denom += sc[k];
    }
    const float inv = RSCALE / fmaxf(denom, 1e-12f);

    // Dense vectorized write: lane l owns experts 4l..4l+3.
    float4 p, m;
    float* pp = reinterpret_cast<float*>(&p);
    float* mm = reinterpret_cast<float*>(&m);
#pragma unroll
    for (int c = 0; c < 4; ++c) {
        const int e = lane * 4 + c;
        float pv = 0.0f, mv = 0.0f;
#pragma unroll
        for (int k = 0; k < TOPK; ++k) {
            if (eidx[k] == e) { pv = sc[k] * inv; mv = 1.0f; }
        }
        pp[c] = pv; mm[c] = mv;
    }
    reinterpret_cast<float4*>(out + (size_t)n * NEXP)[lane] = p;
    reinterpret_cast<float4*>(out + (size_t)(N + n) * NEXP)[lane] = m;
}

extern "C" void kernel_launch(void* const* d_in, const int* in_sizes, int n_in,
                              void* d_out, int out_size, void* d_ws, size_t ws_size,
                              hipStream_t stream) {
    const float* hidden    = (const float*)d_in[0];
    const int*   token_ids = (const int*)d_in[1];   // int64 in ref -> int32 here
    const float* weight    = (const float*)d_in[2];
    const int*   tid2eid   = (const int*)d_in[3];
    float* out = (float*)d_out;
    const int N = in_sizes[1];  // B*S tokens

    const int nblocks = (N + WPT - 1) / WPT;
    const size_t need = (size_t)NEXP * DIM * sizeof(ushort);  // 1 MiB
    if (ws_size >= need) {
        ushort* wb = (ushort*)d_ws;
        const int n4 = NEXP * DIM / 4;
        convert_weight_kernel<<<(n4 + 255) / 256, 256, 0, stream>>>(weight, wb, n4);
        router_wave_kernel<true><<<nblocks, 256, 0, stream>>>(hidden, token_ids, wb, tid2eid, out, N);
    } else {
        router_wave_kernel<false><<<nblocks, 256, 0, stream>>>(hidden, token_ids, weight, tid2eid, out, N);
    }
}

// Round 5
// 43.333 us; speedup vs baseline: 1.2436x; 1.2034x over previous
//
#include <hip/hip_runtime.h>
#include <hip/hip_bf16.h>
#include <hip/hip_fp16.h>

// DeepseekV4HashRouter: B=4,S=4096,D=2048,E=256,K=8,V=128000
#define DIM    2048
#define NEXP   256
#define TOPK   8
#define RSCALE 2.5f
#define WPT    4  // waves (tokens) per 256-thread block

typedef _Float16 h2 __attribute__((ext_vector_type(2)));

__device__ __forceinline__ float dot2(h2 a, h2 b, float c) {
#if __has_builtin(__builtin_amdgcn_fdot2)
    return __builtin_amdgcn_fdot2(a, b, c, false);
#else
    return c + (float)a[0] * (float)b[0] + (float)a[1] * (float)b[1];
#endif
}

__device__ __forceinline__ h2 cvt_pk(float x, float y) {
#if __has_builtin(__builtin_amdgcn_cvt_pkrtz)
    return __builtin_bit_cast(h2, __builtin_amdgcn_cvt_pkrtz(x, y));
#else
    h2 r; r[0] = (_Float16)x; r[1] = (_Float16)y; return r;
#endif
}

__device__ __forceinline__ h2 as_h2(unsigned int u) {
    return __builtin_bit_cast(h2, u);
}

__global__ __launch_bounds__(256) void convert_weight_f16(
    const float* __restrict__ w, unsigned int* __restrict__ wh, int n4) {
    int i = blockIdx.x * blockDim.x + threadIdx.x;  // over float4s
    if (i < n4) {
        float4 f = reinterpret_cast<const float4*>(w)[i];
        uint2 o;
        o.x = __builtin_bit_cast(unsigned int, cvt_pk(f.x, f.y));
        o.y = __builtin_bit_cast(unsigned int, cvt_pk(f.z, f.w));
        reinterpret_cast<uint2*>(wh)[i] = o;
    }
}

// One 64-lane wave per token; f16 weight + v_dot2, tournament reduce.
template <bool F16W>
__global__ __launch_bounds__(256) void router_v3(
    const float* __restrict__ hidden,   // [N, D] fp32
    const int* __restrict__ token_ids,  // [N] int32
    const void* __restrict__ weight,    // [E, D] f16-pairs(u32) or fp32
    const int* __restrict__ tid2eid,    // [V, K] int32
    float* __restrict__ out,            // probs [N,E] then map [N,E]
    int N) {
    const int lane = threadIdx.x & 63;
    const int n = blockIdx.x * WPT + (threadIdx.x >> 6);
    if (n >= N) return;

    // Start the dependent gather chain first.
    const int tid = token_ids[n];
    const int4* erow = reinterpret_cast<const int4*>(tid2eid + (size_t)tid * TOPK);
    const int4 i0 = erow[0];
    const int4 i1 = erow[1];
    const int eidx[TOPK] = {i0.x, i0.y, i0.z, i0.w, i1.x, i1.y, i1.z, i1.w};

    // Lane owns elems {j*512 + lane*8 .. +7}, j=0..3; packed to f16 pairs.
    const float4* h4 = reinterpret_cast<const float4*>(hidden + (size_t)n * DIM);
    h2 hh[16];
#pragma unroll
    for (int j = 0; j < 4; ++j) {
        const float4 a = h4[j * 128 + lane * 2];
        const float4 b = h4[j * 128 + lane * 2 + 1];
        hh[4 * j + 0] = cvt_pk(a.x, a.y);
        hh[4 * j + 1] = cvt_pk(a.z, a.w);
        hh[4 * j + 2] = cvt_pk(b.x, b.y);
        hh[4 * j + 3] = cvt_pk(b.z, b.w);
    }

    float acc[TOPK];
#pragma unroll
    for (int k = 0; k < TOPK; ++k) {
        float s = 0.0f;
        if (F16W) {
            const uint4* wrow = reinterpret_cast<const uint4*>(weight) + (size_t)eidx[k] * (DIM / 8);
#pragma unroll
            for (int j = 0; j < 4; ++j) {
                const uint4 wv = wrow[j * 64 + lane];  // 8 f16, 1KB/wave coalesced
                s = dot2(hh[4 * j + 0], as_h2(wv.x), s);
                s = dot2(hh[4 * j + 1], as_h2(wv.y), s);
                s = dot2(hh[4 * j + 2], as_h2(wv.z), s);
                s = dot2(hh[4 * j + 3], as_h2(wv.w), s);
            }
        } else {
            const float4* wrow = reinterpret_cast<const float4*>(weight) + (size_t)eidx[k] * (DIM / 4);
#pragma unroll
            for (int j = 0; j < 4; ++j) {
                const float4 wa = wrow[j * 128 + lane * 2];
                const float4 wb = wrow[j * 128 + lane * 2 + 1];
                const float4 a = h4[j * 128 + lane * 2];      // L1 re-hit
                const float4 b = h4[j * 128 + lane * 2 + 1];
                s += a.x * wa.x + a.y * wa.y + a.z * wa.z + a.w * wa.w
                   + b.x * wb.x + b.y * wb.y + b.z * wb.z + b.w * wb.w;
            }
        }
        acc[k] = s;
    }

    // Tournament reduce: 8 values/lane -> 1 value/lane in 7 shfls + 3 butterfly.
    const int b0 = lane & 1, b1 = (lane >> 1) & 1, b2 = (lane >> 2) & 1;
    float v4[4];
#pragma unroll
    for (int k = 0; k < 4; ++k) {
        const float send = b0 ? acc[k] : acc[k + 4];
        const float recv = __shfl_xor(send, 1, 64);
        v4[k] = (b0 ? acc[k + 4] : acc[k]) + recv;
    }
    float v2[2];
#pragma unroll
    for (int j = 0; j < 2; ++j) {
        const float send = b1 ? v4[j] : v4[j + 2];
        const float recv = __shfl_xor(send, 2, 64);
        v2[j] = (b1 ? v4[j + 2] : v4[j]) + recv;
    }
    {
        const float send = b2 ? v2[0] : v2[1];
        const float recv = __shfl_xor(send, 4, 64);
        v2[0] = (b2 ? v2[1] : v2[0]) + recv;
    }
    float v = v2[0];
    v += __shfl_xor(v, 8, 64);
    v += __shfl_xor(v, 16, 64);
    v += __shfl_xor(v, 32, 64);
    // Lane l holds logit of expert slot e(l) = 4*b0 + 2*b1 + b2.

    // sqrt(softplus) on all lanes (8 distinct values, no divergence).
    const float sp = fmaxf(v, 0.0f) + log1pf(expf(-fabsf(v)));
    const float score = sqrtf(sp);

    // Gather all 8 slot scores: slot k lives in lane bit-rev3(k).
    float sc[TOPK];
    float denom = 0.0f;
#pragma unroll
    for (int k = 0; k < TOPK; ++k) {
        const int src = ((k >> 2) & 1) | (k & 2) | ((k & 1) << 2);
        sc[k] = __shfl(score, src, 64);
        denom += sc[k];
    }
    const float inv = RSCALE / fmaxf(denom, 1e-12f);

    // Dense vectorized write: lane l owns experts 4l..4l+3.
    float4 p, m;
    float* pp = reinterpret_cast<float*>(&p);
    float* mm = reinterpret_cast<float*>(&m);
#pragma unroll
    for (int c = 0; c < 4; ++c) {
        const int e = lane * 4 + c;
        float pv = 0.0f, mv = 0.0f;
#pragma unroll
        for (int k = 0; k < TOPK; ++k) {
            if (eidx[k] == e) { pv = sc[k] * inv; mv = 1.0f; }
        }
        pp[c] = pv; mm[c] = mv;
    }
    reinterpret_cast<float4*>(out + (size_t)n * NEXP)[lane] = p;
    reinterpret_cast<float4*>(out + (size_t)(N + n) * NEXP)[lane] = m;
}

extern "C" void kernel_launch(void* const* d_in, const int* in_sizes, int n_in,
                              void* d_out, int out_size, void* d_ws, size_t ws_size,
                              hipStream_t stream) {
    const float* hidden    = (const float*)d_in[0];
    const int*   token_ids = (const int*)d_in[1];   // int64 in ref -> int32 here
    const float* weight    = (const float*)d_in[2];
    const int*   tid2eid   = (const int*)d_in[3];
    float* out = (float*)d_out;
    const int N = in_sizes[1];  // B*S tokens

    const int nblocks = (N + WPT - 1) / WPT;
    const size_t need = (size_t)NEXP * DIM * sizeof(unsigned short);  // 1 MiB
    if (ws_size >= need) {
        unsigned int* wh = (unsigned int*)d_ws;
        const int n4 = NEXP * DIM / 4;
        convert_weight_f16<<<(n4 + 255) / 256, 256, 0, stream>>>(weight, wh, n4);
        router_v3<true><<<nblocks, 256, 0, stream>>>(hidden, token_ids, wh, tid2eid, out, N);
    } else {
        router_v3<false><<<nblocks, 256, 0, stream>>>(hidden, token_ids, weight, tid2eid, out, N);
    }
}